// Round 16
// baseline (584.728 us; speedup 1.0000x reference)
//
#include <hip/hip_runtime.h>
#include <math.h>

#define BB 2
#define NN 16384
#define MM 4096
#define C_IN 32
#define D_DIM 64
#define H_DIM 32
#define KNB 16
#define EPSV 1e-5f
#define FLT_BIG 3.0e38f
#define CAPK 128
#define NSPL 4
#define SPTS (NN / NSPL)   // 4096

// stats layout (floats)
#define SPOS_SUM 0
#define SPOS_SQ 32
#define SFEAT_SUM 64
#define SFEAT_SQ 96
#define SSC1_SUM 128
#define SSC1_SQ 192
#define SSC2_SUM 256
#define SSC2_SQ 320
#define SOUT_SUM 384
#define SOUT_SQ 448
#define STATS_LEN 512
#define PA_W 384
#define PB_W 128
#define NBKT 64
#define NBLK (BB * MM / 4)

__device__ __forceinline__ int clampi_r16(int v, int lo, int hi) {
    return v < lo ? lo : (v > hi ? hi : v);
}

// ---------------- prep (merged): transpose + xyz4(|p|^2) + outputs 0&2 + zero stats region ----------------
__global__ __launch_bounds__(256) void prep_r16(const float* __restrict__ feats,
                                                const float* __restrict__ xyz,
                                                const int* __restrict__ sample_idx,
                                                float* __restrict__ featsT,
                                                float* __restrict__ xyz4,
                                                float* __restrict__ statszero,  // stats+stats64A+stats64B+counters
                                                float* __restrict__ out) {
    __shared__ float tile[C_IN][65];
    const int tid = threadIdx.x;
    const int b = blockIdx.x >> 8;
    const int n0 = (blockIdx.x & 255) * 64;
#pragma unroll
    for (int it = 0; it < 8; ++it) {
        int c = (tid >> 6) + 4 * it;
        int n = tid & 63;
        tile[c][n] = feats[((size_t)b * C_IN + c) * NN + n0 + n];
    }
    int e = blockIdx.x * 256 + tid;
    if (e < STATS_LEN + NBKT * PA_W + NBKT * PB_W + 2) statszero[e] = 0.f;
    if (e < BB * NN) {
        float x = xyz[e * 3 + 0], y = xyz[e * 3 + 1], z = xyz[e * 3 + 2];
        xyz4[e * 4 + 0] = x;
        xyz4[e * 4 + 1] = y;
        xyz4[e * 4 + 2] = z;
        xyz4[e * 4 + 3] = x * x + y * y + z * z;
    }
    if (e < BB * MM) {
        int bb2 = e >> 12;
        int sidx = clampi_r16(sample_idx[e], 0, NN - 1);
        const float* p = xyz + (size_t)(bb2 * NN + sidx) * 3;
        out[e * 3 + 0] = p[0];
        out[e * 3 + 1] = p[1];
        out[e * 3 + 2] = p[2];
        out[BB * MM * 3 + BB * D_DIM * MM + e] = (float)sample_idx[e];
    }
    __syncthreads();
#pragma unroll
    for (int it = 0; it < 8; ++it) {
        int c = tid & 31;
        int nn = (tid >> 5) + 8 * it;
        featsT[((size_t)b * NN + n0 + nn) * C_IN + c] = tile[c][nn];
    }
}

// exact full-scan fallback over one split (d2' metric) — essentially never taken
__device__ void knn_fullsplit_r16(const float* __restrict__ base4, int n0,
                                  float m2x, float m2y, float m2z, int lane,
                                  float* __restrict__ outd, int* __restrict__ outi) {
    float d2v[KNB]; int iv[KNB];
#pragma unroll
    for (int i = 0; i < KNB; i++) { d2v[i] = FLT_BIG; iv[i] = 0x7FFFFFFF; }
    float curmax = FLT_BIG; int amax = 0;
    for (int t = 0; t < SPTS / 64; ++t) {
        int n = n0 + lane + t * 64;
        const float4 p = *reinterpret_cast<const float4*>(base4 + (size_t)n * 4);
        float d2 = fmaf(p.x, m2x, p.w);
        d2 = fmaf(p.y, m2y, d2);
        d2 = fmaf(p.z, m2z, d2);
        if (d2 < curmax) {
#pragma unroll
            for (int i = 0; i < KNB; i++)
                if (i == amax) { d2v[i] = d2; iv[i] = n; }
            curmax = d2v[0]; amax = 0;
#pragma unroll
            for (int i = 1; i < KNB; i++)
                if (d2v[i] > curmax) { curmax = d2v[i]; amax = i; }
        }
    }
#pragma unroll
    for (int i = 0; i < KNB; i++) {
#pragma unroll
        for (int j = 0; j < KNB - 1; j++) {
            bool sw = (d2v[j] > d2v[j + 1]) ||
                      (d2v[j] == d2v[j + 1] && iv[j] > iv[j + 1]);
            if (sw) {
                float td = d2v[j]; d2v[j] = d2v[j + 1]; d2v[j + 1] = td;
                int   ti = iv[j];  iv[j]  = iv[j + 1];  iv[j + 1]  = ti;
            }
        }
    }
    float myd = FLT_BIG; int myidx = 0x7FFFFFFF;
#pragma unroll 1
    for (int r = 0; r < KNB; r++) {
        float cv = d2v[0]; int cid = iv[0]; int ml = lane;
#pragma unroll
        for (int off = 32; off > 0; off >>= 1) {
            float ov = __shfl_xor(cv, off);
            int   oid = __shfl_xor(cid, off);
            int   ol = __shfl_xor(ml, off);
            bool take = (ov < cv) || (ov == cv && oid < cid);
            cv = take ? ov : cv; cid = take ? oid : cid; ml = take ? ol : ml;
        }
        if (lane == r) { myd = cv; myidx = cid; }
        if (lane == ml) {
#pragma unroll
            for (int i = 0; i < KNB - 1; i++) { d2v[i] = d2v[i + 1]; iv[i] = iv[i + 1]; }
            d2v[KNB - 1] = FLT_BIG; iv[KNB - 1] = 0x7FFFFFFF;
        }
    }
    if (lane < KNB) { outd[lane] = myd; outi[lane] = myidx; }
}

// ---------------- KNN split pass (r14-frozen: full-split phase 1, unroll 8, 18-iter bound) ----------------
__global__ __launch_bounds__(256) void knn_r16(const float* __restrict__ xyz4,
                                               const int* __restrict__ sample_idx,
                                               float* __restrict__ cand_d,
                                               int* __restrict__ cand_i) {
    __shared__ float bufd[16][CAPK];
    __shared__ int   bufi[16][CAPK];
    __shared__ int   cnt_lds[16];
    const int tid = threadIdx.x;
    const int w = tid >> 6, lane = tid & 63;
    const int split = blockIdx.x & (NSPL - 1);
    const int qgrp = blockIdx.x >> 2;
    const int qbase = qgrp * 16 + w * 4;
    const int b = qbase >> 12;
    const int n0 = split * SPTS;
    if (tid < 16) cnt_lds[tid] = 0;
    __syncthreads();
    const float* base4 = xyz4 + (size_t)b * NN * 4;
    const float4* p4 = reinterpret_cast<const float4*>(base4) + n0 + lane;

    float m2x[4], m2y[4], m2z[4], md[4], v16[4];
#pragma unroll
    for (int j = 0; j < 4; j++) {
        int s = clampi_r16(sample_idx[qbase + j], 0, NN - 1);
        m2x[j] = -2.f * base4[(size_t)s * 4 + 0];
        m2y[j] = -2.f * base4[(size_t)s * 4 + 1];
        m2z[j] = -2.f * base4[(size_t)s * 4 + 2];
        md[j] = FLT_BIG;
    }
#pragma unroll 8
    for (int it = 0; it < SPTS / 64; ++it) {
        const float4 p = p4[(size_t)it * 64];
#pragma unroll
        for (int j = 0; j < 4; j++) {
            float t = fmaf(p.x, m2x[j], p.w);
            t = fmaf(p.y, m2y[j], t);
            t = fmaf(p.z, m2z[j], t);
            md[j] = fminf(md[j], t);
        }
    }
#pragma unroll 1
    for (int j = 0; j < 4; j++) {
        unsigned fb = __float_as_uint(md[j]);
        unsigned key = (fb & 0x80000000u) ? ~fb : (fb | 0x80000000u);
        unsigned lo = 0u, hi = 0xFFFFFFFFu;
#pragma unroll 1
        for (int itb = 0; itb < 18; ++itb) {
            unsigned mid = lo + ((hi - lo) >> 1);
            unsigned long long bal = __ballot(key <= mid);
            int c = __popcll(bal);
            if (c >= KNB) hi = mid; else lo = mid + 1;
        }
        unsigned vb = (hi & 0x80000000u) ? (hi & 0x7FFFFFFFu) : ~hi;
        v16[j] = __uint_as_float(vb);
    }
#pragma unroll 4
    for (int it = 0; it < SPTS / 64; ++it) {
        const float4 p = p4[(size_t)it * 64];
        const int n = n0 + lane + it * 64;
#pragma unroll
        for (int j = 0; j < 4; j++) {
            float t = fmaf(p.x, m2x[j], p.w);
            t = fmaf(p.y, m2y[j], t);
            t = fmaf(p.z, m2z[j], t);
            if (t <= v16[j]) {
                int pos = atomicAdd(&cnt_lds[w * 4 + j], 1);
                if (pos < CAPK) { bufd[w * 4 + j][pos] = t; bufi[w * 4 + j][pos] = n; }
            }
        }
    }
    __threadfence_block();
#pragma unroll 1
    for (int j = 0; j < 4; j++) {
        const int qi = w * 4 + j;
        const int cnt = cnt_lds[qi];
        const int q = qbase + j;
        float* outd = cand_d + ((size_t)q * NSPL + split) * KNB;
        int*   outi = cand_i + ((size_t)q * NSPL + split) * KNB;
        if (cnt <= CAPK) {
#pragma unroll 1
            for (int half = 0; half < 2; ++half) {
                int i = lane + 64 * half;
                if (i < cnt) {
                    float di = bufd[qi][i]; int xi = bufi[qi][i];
                    int rank = 0;
                    for (int t = 0; t < cnt; ++t) {
                        float dt = bufd[qi][t]; int xt = bufi[qi][t];
                        rank += (dt < di || (dt == di && xt < xi)) ? 1 : 0;
                    }
                    if (rank < KNB) { outd[rank] = di; outi[rank] = xi; }
                }
            }
        } else {
            knn_fullsplit_r16(base4, n0, m2x[j], m2y[j], m2z[j], lane, outd, outi);
        }
    }
}

// pre-BN pos/feat matmul for one (k,h) pair
__device__ __forceinline__ void prebn_r16(const float (*posf)[12], const float (*nf)[C_IN],
                                          int k, int h,
                                          const float* __restrict__ W_pos, const float* __restrict__ b_pos,
                                          const float* __restrict__ W_feat, const float* __restrict__ b_feat,
                                          float* a_out, float* f_out) {
    float4 p0 = *reinterpret_cast<const float4*>(&posf[k][0]);
    float4 p1 = *reinterpret_cast<const float4*>(&posf[k][4]);
    float p8 = posf[k][8], p9 = posf[k][9];
    float a = b_pos[h];
    a += p0.x * W_pos[0 * H_DIM + h]; a += p0.y * W_pos[1 * H_DIM + h];
    a += p0.z * W_pos[2 * H_DIM + h]; a += p0.w * W_pos[3 * H_DIM + h];
    a += p1.x * W_pos[4 * H_DIM + h]; a += p1.y * W_pos[5 * H_DIM + h];
    a += p1.z * W_pos[6 * H_DIM + h]; a += p1.w * W_pos[7 * H_DIM + h];
    a += p8 * W_pos[8 * H_DIM + h];   a += p9 * W_pos[9 * H_DIM + h];
    float f = b_feat[h];
#pragma unroll
    for (int j4 = 0; j4 < C_IN / 4; ++j4) {
        float4 c = *reinterpret_cast<const float4*>(&nf[k][j4 * 4]);
        f += c.x * W_feat[(j4 * 4 + 0) * H_DIM + h];
        f += c.y * W_feat[(j4 * 4 + 1) * H_DIM + h];
        f += c.z * W_feat[(j4 * 4 + 2) * H_DIM + h];
        f += c.w * W_feat[(j4 * 4 + 3) * H_DIM + h];
    }
    *a_out = a; *f_out = f;
}

// ---------------- stage A: merge + gather + pre-BN + combpre + fused stats reduction ----------------
__global__ __launch_bounds__(256) void stageA_r16(const float* __restrict__ xyz4,
                                                  const int* __restrict__ sample_idx,
                                                  const float* __restrict__ featsT,
                                                  const float* __restrict__ cand_d,
                                                  const int* __restrict__ cand_i,
                                                  const float* __restrict__ W_pos, const float* __restrict__ b_pos,
                                                  const float* __restrict__ W_feat, const float* __restrict__ b_feat,
                                                  const float* __restrict__ W_sc1, const float* __restrict__ W_sc2,
                                                  float* __restrict__ combpre,
                                                  float* __restrict__ sc1_pre, float* __restrict__ sc2_pre,
                                                  float* __restrict__ stats,
                                                  float* __restrict__ stats64A,
                                                  int* __restrict__ cntA) {
    __shared__ int   idxs[4][KNB];
    __shared__ float sd[4][64];
    __shared__ int   si[4][64];
    __shared__ __align__(16) float posf[4][KNB][12];
    __shared__ __align__(16) float nf[4][KNB][C_IN];
    __shared__ float meanf[4][C_IN];
    __shared__ float centerf[4][C_IN];
    __shared__ float posS[4][H_DIM], posQ[4][H_DIM], featS[4][H_DIM], featQ[4][H_DIM];
    __shared__ float s1S[4][D_DIM], s1Q[4][D_DIM], s2S[4][D_DIM], s2Q[4][D_DIM];
    __shared__ int islast;
    const int tid = threadIdx.x;
    const int w = tid >> 6, lane = tid & 63;
    const int q = blockIdx.x * 4 + w;
    const int b = q >> 12;
    const int sidx = clampi_r16(sample_idx[q], 0, NN - 1);
    const float* base4 = xyz4 + (size_t)b * NN * 4;

    float d = cand_d[(size_t)q * 64 + lane];
    int   i = cand_i[(size_t)q * 64 + lane];
    float qx = base4[(size_t)sidx * 4 + 0];
    float qy = base4[(size_t)sidx * 4 + 1];
    float qz = base4[(size_t)sidx * 4 + 2];
    float cfv = 0.f;
    if (lane < C_IN) cfv = featsT[((size_t)b * NN + sidx) * C_IN + lane];

    {
        sd[w][lane] = d; si[w][lane] = i;
        __syncthreads();
        int rank = 0;
#pragma unroll
        for (int t = 0; t < 64; ++t) {
            float dt = sd[w][t]; int it = si[w][t];
            rank += (dt < d || (dt == d && it < i)) ? 1 : 0;
        }
        if (rank < KNB) idxs[w][rank] = i;
        if (lane < C_IN) centerf[w][lane] = cfv;
        __syncthreads();
    }

    if (lane < KNB) {
        int idx = clampi_r16(idxs[w][lane], 0, NN - 1);
        float nx = base4[(size_t)idx * 4 + 0];
        float ny = base4[(size_t)idx * 4 + 1];
        float nz = base4[(size_t)idx * 4 + 2];
        float rx = qx - nx, ry = qy - ny, rz = qz - nz;
        float dist = sqrtf(rx * rx + ry * ry + rz * rz);
        posf[w][lane][0] = qx; posf[w][lane][1] = qy; posf[w][lane][2] = qz;
        posf[w][lane][3] = nx; posf[w][lane][4] = ny; posf[w][lane][5] = nz;
        posf[w][lane][6] = rx; posf[w][lane][7] = ry; posf[w][lane][8] = rz;
        posf[w][lane][9] = dist; posf[w][lane][10] = 0.f; posf[w][lane][11] = 0.f;
    }
    __syncthreads();
    const float* fT = featsT + (size_t)b * NN * C_IN;
#pragma unroll
    for (int ii = 0; ii < 2; ++ii) {
        int e4 = lane + 64 * ii;
        int k = e4 >> 3, c4 = e4 & 7;
        const float4 v = *reinterpret_cast<const float4*>(fT + (size_t)idxs[w][k] * C_IN + c4 * 4);
        *reinterpret_cast<float4*>(&nf[w][k][c4 * 4]) = v;
    }
    __syncthreads();

    const int h = lane & 31;
    float sP = 0.f, qP = 0.f, sF = 0.f, qF = 0.f;
    float* cp = combpre + (size_t)q * (KNB * D_DIM);
#pragma unroll
    for (int i2 = 0; i2 < 8; i2++) {
        int k = ((lane + 64 * i2) >> 5);
        float a, f;
        prebn_r16(posf[w], nf[w], k, h, W_pos, b_pos, W_feat, b_feat, &a, &f);
        sP += a; qP += a * a;
        sF += f; qF += f * f;
        cp[k * D_DIM + h] = f;
        cp[k * D_DIM + H_DIM + h] = a;
    }
    sP += __shfl_xor(sP, 32); qP += __shfl_xor(qP, 32);
    sF += __shfl_xor(sF, 32); qF += __shfl_xor(qF, 32);
    if (lane < H_DIM) {
        posS[w][h] = sP; posQ[w][h] = qP; featS[w][h] = sF; featQ[w][h] = qF;
    }
    if (lane < C_IN) {
        float s = 0.f;
#pragma unroll
        for (int k = 0; k < KNB; k++) s += nf[w][k][lane];
        meanf[w][lane] = s * (1.f / (float)KNB);
    }
    __syncthreads();
    {
        float a = 0.f, c2 = 0.f;
#pragma unroll
        for (int j = 0; j < C_IN; j++) {
            a  += meanf[w][j]   * W_sc1[j * D_DIM + lane];
            c2 += centerf[w][j] * W_sc2[j * D_DIM + lane];
        }
        sc1_pre[(size_t)q * D_DIM + lane] = a;
        sc2_pre[(size_t)q * D_DIM + lane] = c2;
        s1S[w][lane] = a;  s1Q[w][lane] = a * a;
        s2S[w][lane] = c2; s2Q[w][lane] = c2 * c2;
    }
    __syncthreads();
    // bucket-atomic block partials (depth NBLK/NBKT = 32 per address)
    float* rowA = stats64A + (size_t)(blockIdx.x & (NBKT - 1)) * PA_W;
    if (tid < H_DIM) {
        atomicAdd(&rowA[SPOS_SUM + tid],  posS[0][tid] + posS[1][tid] + posS[2][tid] + posS[3][tid]);
        atomicAdd(&rowA[SPOS_SQ + tid],   posQ[0][tid] + posQ[1][tid] + posQ[2][tid] + posQ[3][tid]);
        atomicAdd(&rowA[SFEAT_SUM + tid], featS[0][tid] + featS[1][tid] + featS[2][tid] + featS[3][tid]);
        atomicAdd(&rowA[SFEAT_SQ + tid],  featQ[0][tid] + featQ[1][tid] + featQ[2][tid] + featQ[3][tid]);
    } else if (tid < 128) {
        int dd = tid - 64;
        atomicAdd(&rowA[SSC1_SUM + dd], s1S[0][dd] + s1S[1][dd] + s1S[2][dd] + s1S[3][dd]);
        atomicAdd(&rowA[SSC1_SQ + dd],  s1Q[0][dd] + s1Q[1][dd] + s1Q[2][dd] + s1Q[3][dd]);
    } else if (tid < 192) {
        int dd = tid - 128;
        atomicAdd(&rowA[SSC2_SUM + dd], s2S[0][dd] + s2S[1][dd] + s2S[2][dd] + s2S[3][dd]);
        atomicAdd(&rowA[SSC2_SQ + dd],  s2Q[0][dd] + s2Q[1][dd] + s2Q[2][dd] + s2Q[3][dd]);
    }
    __threadfence();
    if (tid == 0) islast = (atomicAdd(cntA, 1) == NBLK - 1);
    __syncthreads();
    if (islast) {
        __threadfence();
        for (int c = tid; c < PA_W; c += 256) {
            float s = 0.f;
            for (int r = 0; r < NBKT; ++r) s += stats64A[(size_t)r * PA_W + c];
            stats[c] = s;                      // stats[0..383] = SPOS..SSC2
        }
    }
}

// ---------------- stage B: stream combpre -> BN -> softmax -> pooled -> W_out + fused out-stats ----------------
__global__ __launch_bounds__(256) void stageB_r16(const float* __restrict__ combpre,
                                                  const float* __restrict__ g_pos, const float* __restrict__ be_pos,
                                                  const float* __restrict__ g_feat, const float* __restrict__ be_feat,
                                                  const float* __restrict__ W_score, const float* __restrict__ W_out,
                                                  float* __restrict__ stats,
                                                  float* __restrict__ out_pre,
                                                  float* __restrict__ stats64B,
                                                  int* __restrict__ cntB) {
    __shared__ __align__(16) float comb[4][KNB][D_DIM];
    __shared__ float scl[D_DIM], shf[D_DIM];
    __shared__ float pooled[4][D_DIM];
    __shared__ float oS[4][D_DIM], oQ[4][D_DIM];
    __shared__ int islast;
    const int tid = threadIdx.x;
    const int w = tid >> 6, lane = tid & 63;
    const int q = blockIdx.x * 4 + w;

    if (tid < D_DIM) {
        const float inv1 = 1.f / (float)(BB * MM * KNB);
        float mean, var, g, bb;
        if (tid < H_DIM) {
            mean = stats[SFEAT_SUM + tid] * inv1;
            var  = fmaxf(stats[SFEAT_SQ + tid] * inv1 - mean * mean, 0.f);
            g = g_feat[tid]; bb = be_feat[tid];
        } else {
            int h = tid - H_DIM;
            mean = stats[SPOS_SUM + h] * inv1;
            var  = fmaxf(stats[SPOS_SQ + h] * inv1 - mean * mean, 0.f);
            g = g_pos[h]; bb = be_pos[h];
        }
        float s = g * rsqrtf(var + EPSV);
        scl[tid] = s;
        shf[tid] = bb - mean * s;
    }
    __syncthreads();

    const float4* src = reinterpret_cast<const float4*>(combpre + (size_t)blockIdx.x * 4 * KNB * D_DIM);
#pragma unroll
    for (int i = 0; i < 4; ++i) {
        int f = tid + 256 * i;
        int qloc = f >> 8;
        int k = (f >> 4) & 15;
        int j4 = f & 15;
        float4 v = src[f];
        int j = j4 * 4;
        v.x = fmaxf(v.x * scl[j + 0] + shf[j + 0], 0.f);
        v.y = fmaxf(v.y * scl[j + 1] + shf[j + 1], 0.f);
        v.z = fmaxf(v.z * scl[j + 2] + shf[j + 2], 0.f);
        v.w = fmaxf(v.w * scl[j + 3] + shf[j + 3], 0.f);
        *reinterpret_cast<float4*>(&comb[qloc][k][j]) = v;
    }
    __syncthreads();

    const int d = lane;
    float s[KNB];
#pragma unroll
    for (int k = 0; k < KNB; k++) s[k] = 0.f;
#pragma unroll 4
    for (int j4 = 0; j4 < D_DIM / 4; ++j4) {
        float w0 = W_score[(j4 * 4 + 0) * D_DIM + d];
        float w1 = W_score[(j4 * 4 + 1) * D_DIM + d];
        float w2 = W_score[(j4 * 4 + 2) * D_DIM + d];
        float w3 = W_score[(j4 * 4 + 3) * D_DIM + d];
#pragma unroll
        for (int k = 0; k < KNB; k++) {
            float4 cb = *reinterpret_cast<const float4*>(&comb[w][k][j4 * 4]);
            s[k] += cb.x * w0 + cb.y * w1 + cb.z * w2 + cb.w * w3;
        }
    }
    float mx = s[0];
#pragma unroll
    for (int k = 1; k < KNB; k++) mx = fmaxf(mx, s[k]);
    float sum = 0.f;
#pragma unroll
    for (int k = 0; k < KNB; k++) { s[k] = __expf(s[k] - mx); sum += s[k]; }
    float inv = 1.f / sum;
    float pv = 0.f;
#pragma unroll
    for (int k = 0; k < KNB; k++) pv += s[k] * inv * comb[w][k][d];
    pooled[w][d] = pv;
    __syncthreads();
    float o = 0.f;
#pragma unroll
    for (int dd = 0; dd < D_DIM; dd++) o += pooled[w][dd] * W_out[dd * D_DIM + d];
    out_pre[(size_t)q * D_DIM + d] = o;
    oS[w][d] = o; oQ[w][d] = o * o;
    __syncthreads();
    float* rowB = stats64B + (size_t)(blockIdx.x & (NBKT - 1)) * PB_W;
    if (tid < D_DIM) {
        atomicAdd(&rowB[tid], oS[0][tid] + oS[1][tid] + oS[2][tid] + oS[3][tid]);
    } else if (tid < 2 * D_DIM) {
        int dd = tid - D_DIM;
        atomicAdd(&rowB[D_DIM + dd], oQ[0][dd] + oQ[1][dd] + oQ[2][dd] + oQ[3][dd]);
    }
    __threadfence();
    if (tid == 0) islast = (atomicAdd(cntB, 1) == NBLK - 1);
    __syncthreads();
    if (islast) {
        __threadfence();
        if (tid < PB_W) {
            float ssum = 0.f;
            for (int r = 0; r < NBKT; ++r) ssum += stats64B[(size_t)r * PB_W + tid];
            stats[SOUT_SUM + tid] = ssum;      // stats[384..511]
        }
    }
}

// ---------------- final ----------------
__global__ __launch_bounds__(256) void final_r16(const float* __restrict__ out_pre,
                                                 const float* __restrict__ sc1_pre,
                                                 const float* __restrict__ sc2_pre,
                                                 const float* __restrict__ stats,
                                                 const float* __restrict__ g_out, const float* __restrict__ be_out,
                                                 const float* __restrict__ g_sc1, const float* __restrict__ be_sc1,
                                                 const float* __restrict__ g_sc2, const float* __restrict__ be_sc2,
                                                 float* __restrict__ out) {
    __shared__ float yt[64][65];
    const int tid = threadIdx.x;
    const int blk = blockIdx.x;
    const int b = blk >> 6;
    const int m0 = (blk & 63) * 64;
    const int d = tid & 63;

    const float invn = 1.f / (float)(BB * MM);
    float mo = stats[SOUT_SUM + d] * invn;
    float vo = fmaxf(stats[SOUT_SQ + d] * invn - mo * mo, 0.f);
    float so = g_out[d] * rsqrtf(vo + EPSV);
    float oo = be_out[d] - mo * so;
    float m1 = stats[SSC1_SUM + d] * invn;
    float v1 = fmaxf(stats[SSC1_SQ + d] * invn - m1 * m1, 0.f);
    float s1 = g_sc1[d] * rsqrtf(v1 + EPSV);
    float o1 = be_sc1[d] - m1 * s1;
    float m2 = stats[SSC2_SUM + d] * invn;
    float v2 = fmaxf(stats[SSC2_SQ + d] * invn - m2 * m2, 0.f);
    float s2 = g_sc2[d] * rsqrtf(v2 + EPSV);
    float o2 = be_sc2[d] - m2 * s2;

#pragma unroll
    for (int p = 0; p < 16; p++) {
        int ml = (tid >> 6) + 4 * p;
        size_t q = (size_t)b * MM + m0 + ml;
        float x_out = fmaxf(out_pre[q * D_DIM + d] * so + oo, 0.f);
        float x1 = sc1_pre[q * D_DIM + d] * s1 + o1;
        float x2 = sc2_pre[q * D_DIM + d] * s2 + o2;
        yt[ml][d] = fmaxf(x_out + x1 + x2, 0.f);
    }
    __syncthreads();
#pragma unroll
    for (int p = 0; p < 16; p++) {
        int dr = (tid >> 6) + 4 * p;
        int mc = tid & 63;
        out[BB * MM * 3 + (size_t)b * (D_DIM * MM) + (size_t)dr * MM + m0 + mc] = yt[mc][dr];
    }
}

extern "C" void kernel_launch(void* const* d_in, const int* in_sizes, int n_in,
                              void* d_out, int out_size, void* d_ws, size_t ws_size,
                              hipStream_t stream) {
    const float* xyz        = (const float*)d_in[0];
    const float* feats      = (const float*)d_in[1];
    const int*   sample_idx = (const int*)d_in[2];
    const float* W_pos  = (const float*)d_in[3];
    const float* b_pos  = (const float*)d_in[4];
    const float* g_pos  = (const float*)d_in[5];
    const float* be_pos = (const float*)d_in[6];
    const float* W_feat  = (const float*)d_in[7];
    const float* b_feat  = (const float*)d_in[8];
    const float* g_feat  = (const float*)d_in[9];
    const float* be_feat = (const float*)d_in[10];
    const float* W_score = (const float*)d_in[11];
    const float* W_out  = (const float*)d_in[12];
    const float* g_out  = (const float*)d_in[13];
    const float* be_out = (const float*)d_in[14];
    const float* W_sc1  = (const float*)d_in[15];
    const float* g_sc1  = (const float*)d_in[16];
    const float* be_sc1 = (const float*)d_in[17];
    const float* W_sc2  = (const float*)d_in[18];
    const float* g_sc2  = (const float*)d_in[19];
    const float* be_sc2 = (const float*)d_in[20];

    float* out = (float*)d_out;
    float* ws = (float*)d_ws;

    float* featsT   = ws;                                    // 1,048,576
    float* xyz4     = featsT + 1048576;                      //   131,072
    float* sc1_pre  = xyz4 + 131072;                         //   524,288
    float* sc2_pre  = sc1_pre + 524288;                      //   524,288
    float* out_pre  = sc2_pre + 524288;                      //   524,288
    float* stats    = out_pre + 524288;                      //       512
    float* stats64A = stats + STATS_LEN;                     //    24,576 (64*384)
    float* stats64B = stats64A + NBKT * PA_W;                //     8,192 (64*128)
    int*   counters = (int*)(stats64B + NBKT * PB_W);        //         2
    float* cand_d   = (float*)(counters + 2);                //   524,288
    int*   cand_i   = (int*)(cand_d + (size_t)BB * MM * NSPL * KNB);   // 524,288 ints
    float* combpre  = (float*)(cand_i + (size_t)BB * MM * NSPL * KNB); // 8,388,608 (32 MB)

    prep_r16<<<BB * (NN / 64), 256, 0, stream>>>(feats, xyz, sample_idx,
                                                 featsT, xyz4, stats, out);

    knn_r16<<<(BB * MM / 16) * NSPL, 256, 0, stream>>>(xyz4, sample_idx, cand_d, cand_i);

    stageA_r16<<<NBLK, 256, 0, stream>>>(xyz4, sample_idx, featsT, cand_d, cand_i,
                                         W_pos, b_pos, W_feat, b_feat, W_sc1, W_sc2,
                                         combpre, sc1_pre, sc2_pre,
                                         stats, stats64A, counters + 0);

    stageB_r16<<<NBLK, 256, 0, stream>>>(combpre,
                                         g_pos, be_pos, g_feat, be_feat,
                                         W_score, W_out, stats, out_pre,
                                         stats64B, counters + 1);

    final_r16<<<BB * (MM / 64), 256, 0, stream>>>(out_pre, sc1_pre, sc2_pre, stats,
                                                  g_out, be_out, g_sc1, be_sc1, g_sc2, be_sc2, out);
}

// Round 17
// 262.680 us; speedup vs baseline: 2.2260x; 2.2260x over previous
//
#include <hip/hip_runtime.h>
#include <math.h>

#define BB 2
#define NN 16384
#define MM 4096
#define C_IN 32
#define D_DIM 64
#define H_DIM 32
#define KNB 16
#define EPSV 1e-5f
#define FLT_BIG 3.0e38f
#define CAPK 128
#define NSPL 4
#define SPTS (NN / NSPL)   // 4096

// stats layout (floats)
#define SPOS_SUM 0
#define SPOS_SQ 32
#define SFEAT_SUM 64
#define SFEAT_SQ 96
#define SSC1_SUM 128
#define SSC1_SQ 192
#define SSC2_SUM 256
#define SSC2_SQ 320
#define SOUT_SUM 384
#define SOUT_SQ 448
#define STATS_LEN 512
#define PA_W 384
#define PB_W 128
#define NBLK (BB * MM / 4)

__device__ __forceinline__ int clampi_r17(int v, int lo, int hi) {
    return v < lo ? lo : (v > hi ? hi : v);
}

// ---------------- prep (merged): transpose + xyz4(|p|^2) + outputs 0&2 + stats zero ----------------
__global__ __launch_bounds__(256) void prep_r17(const float* __restrict__ feats,
                                                const float* __restrict__ xyz,
                                                const int* __restrict__ sample_idx,
                                                float* __restrict__ featsT,
                                                float* __restrict__ xyz4,
                                                float* __restrict__ stats,
                                                float* __restrict__ out) {
    __shared__ float tile[C_IN][65];
    const int tid = threadIdx.x;
    const int b = blockIdx.x >> 8;
    const int n0 = (blockIdx.x & 255) * 64;
#pragma unroll
    for (int it = 0; it < 8; ++it) {
        int c = (tid >> 6) + 4 * it;
        int n = tid & 63;
        tile[c][n] = feats[((size_t)b * C_IN + c) * NN + n0 + n];
    }
    int e = blockIdx.x * 256 + tid;
    if (e < STATS_LEN) stats[e] = 0.f;
    if (e < BB * NN) {
        float x = xyz[e * 3 + 0], y = xyz[e * 3 + 1], z = xyz[e * 3 + 2];
        xyz4[e * 4 + 0] = x;
        xyz4[e * 4 + 1] = y;
        xyz4[e * 4 + 2] = z;
        xyz4[e * 4 + 3] = x * x + y * y + z * z;
    }
    if (e < BB * MM) {
        int bb2 = e >> 12;
        int sidx = clampi_r17(sample_idx[e], 0, NN - 1);
        const float* p = xyz + (size_t)(bb2 * NN + sidx) * 3;
        out[e * 3 + 0] = p[0];
        out[e * 3 + 1] = p[1];
        out[e * 3 + 2] = p[2];
        out[BB * MM * 3 + BB * D_DIM * MM + e] = (float)sample_idx[e];
    }
    __syncthreads();
#pragma unroll
    for (int it = 0; it < 8; ++it) {
        int c = tid & 31;
        int nn = (tid >> 5) + 8 * it;
        featsT[((size_t)b * NN + n0 + nn) * C_IN + c] = tile[c][nn];
    }
}

// exact full-scan fallback over one split (d2' metric) — essentially never taken
__device__ void knn_fullsplit_r17(const float* __restrict__ base4, int n0,
                                  float m2x, float m2y, float m2z, int lane,
                                  float* __restrict__ outd, int* __restrict__ outi) {
    float d2v[KNB]; int iv[KNB];
#pragma unroll
    for (int i = 0; i < KNB; i++) { d2v[i] = FLT_BIG; iv[i] = 0x7FFFFFFF; }
    float curmax = FLT_BIG; int amax = 0;
    for (int t = 0; t < SPTS / 64; ++t) {
        int n = n0 + lane + t * 64;
        const float4 p = *reinterpret_cast<const float4*>(base4 + (size_t)n * 4);
        float d2 = fmaf(p.x, m2x, p.w);
        d2 = fmaf(p.y, m2y, d2);
        d2 = fmaf(p.z, m2z, d2);
        if (d2 < curmax) {
#pragma unroll
            for (int i = 0; i < KNB; i++)
                if (i == amax) { d2v[i] = d2; iv[i] = n; }
            curmax = d2v[0]; amax = 0;
#pragma unroll
            for (int i = 1; i < KNB; i++)
                if (d2v[i] > curmax) { curmax = d2v[i]; amax = i; }
        }
    }
#pragma unroll
    for (int i = 0; i < KNB; i++) {
#pragma unroll
        for (int j = 0; j < KNB - 1; j++) {
            bool sw = (d2v[j] > d2v[j + 1]) ||
                      (d2v[j] == d2v[j + 1] && iv[j] > iv[j + 1]);
            if (sw) {
                float td = d2v[j]; d2v[j] = d2v[j + 1]; d2v[j + 1] = td;
                int   ti = iv[j];  iv[j]  = iv[j + 1];  iv[j + 1]  = ti;
            }
        }
    }
    float myd = FLT_BIG; int myidx = 0x7FFFFFFF;
#pragma unroll 1
    for (int r = 0; r < KNB; r++) {
        float cv = d2v[0]; int cid = iv[0]; int ml = lane;
#pragma unroll
        for (int off = 32; off > 0; off >>= 1) {
            float ov = __shfl_xor(cv, off);
            int   oid = __shfl_xor(cid, off);
            int   ol = __shfl_xor(ml, off);
            bool take = (ov < cv) || (ov == cv && oid < cid);
            cv = take ? ov : cv; cid = take ? oid : cid; ml = take ? ol : ml;
        }
        if (lane == r) { myd = cv; myidx = cid; }
        if (lane == ml) {
#pragma unroll
            for (int i = 0; i < KNB - 1; i++) { d2v[i] = d2v[i + 1]; iv[i] = iv[i + 1]; }
            d2v[KNB - 1] = FLT_BIG; iv[KNB - 1] = 0x7FFFFFFF;
        }
    }
    if (lane < KNB) { outd[lane] = myd; outi[lane] = myidx; }
}

// ---------------- KNN split pass (full-split phase 1, unroll 8, 18-iter bound) ----------------
__global__ __launch_bounds__(256) void knn_r17(const float* __restrict__ xyz4,
                                               const int* __restrict__ sample_idx,
                                               float* __restrict__ cand_d,
                                               int* __restrict__ cand_i) {
    __shared__ float bufd[16][CAPK];
    __shared__ int   bufi[16][CAPK];
    __shared__ int   cnt_lds[16];
    const int tid = threadIdx.x;
    const int w = tid >> 6, lane = tid & 63;
    const int split = blockIdx.x & (NSPL - 1);
    const int qgrp = blockIdx.x >> 2;
    const int qbase = qgrp * 16 + w * 4;
    const int b = qbase >> 12;
    const int n0 = split * SPTS;
    if (tid < 16) cnt_lds[tid] = 0;
    __syncthreads();
    const float* base4 = xyz4 + (size_t)b * NN * 4;
    const float4* p4 = reinterpret_cast<const float4*>(base4) + n0 + lane;

    float m2x[4], m2y[4], m2z[4], md[4], v16[4];
#pragma unroll
    for (int j = 0; j < 4; j++) {
        int s = clampi_r17(sample_idx[qbase + j], 0, NN - 1);
        m2x[j] = -2.f * base4[(size_t)s * 4 + 0];
        m2y[j] = -2.f * base4[(size_t)s * 4 + 1];
        m2z[j] = -2.f * base4[(size_t)s * 4 + 2];
        md[j] = FLT_BIG;
    }
    // phase 1: per-lane min of d2' over FULL split; unroll 8 hides L2 latency
#pragma unroll 8
    for (int it = 0; it < SPTS / 64; ++it) {
        const float4 p = p4[(size_t)it * 64];
#pragma unroll
        for (int j = 0; j < 4; j++) {
            float t = fmaf(p.x, m2x[j], p.w);
            t = fmaf(p.y, m2y[j], t);
            t = fmaf(p.z, m2z[j], t);
            md[j] = fminf(md[j], t);
        }
    }
    // bound: 18-iter ballot binary search (invariant count(key<=hi) >= 16 every step
    // => early stop is a valid, ~0.2%-loose bound; keeps cnt ~ 20)
#pragma unroll 1
    for (int j = 0; j < 4; j++) {
        unsigned fb = __float_as_uint(md[j]);
        unsigned key = (fb & 0x80000000u) ? ~fb : (fb | 0x80000000u);
        unsigned lo = 0u, hi = 0xFFFFFFFFu;
#pragma unroll 1
        for (int itb = 0; itb < 18; ++itb) {
            unsigned mid = lo + ((hi - lo) >> 1);
            unsigned long long bal = __ballot(key <= mid);
            int c = __popcll(bal);
            if (c >= KNB) hi = mid; else lo = mid + 1;
        }
        unsigned vb = (hi & 0x80000000u) ? (hi & 0x7FFFFFFFu) : ~hi;
        v16[j] = __uint_as_float(vb);
    }
    // phase 2: collect candidates d2' <= bound
#pragma unroll 4
    for (int it = 0; it < SPTS / 64; ++it) {
        const float4 p = p4[(size_t)it * 64];
        const int n = n0 + lane + it * 64;
#pragma unroll
        for (int j = 0; j < 4; j++) {
            float t = fmaf(p.x, m2x[j], p.w);
            t = fmaf(p.y, m2y[j], t);
            t = fmaf(p.z, m2z[j], t);
            if (t <= v16[j]) {
                int pos = atomicAdd(&cnt_lds[w * 4 + j], 1);
                if (pos < CAPK) { bufd[w * 4 + j][pos] = t; bufi[w * 4 + j][pos] = n; }
            }
        }
    }
    __threadfence_block();
    // phase 3: per-split exact top-16 by rank
#pragma unroll 1
    for (int j = 0; j < 4; j++) {
        const int qi = w * 4 + j;
        const int cnt = cnt_lds[qi];
        const int q = qbase + j;
        float* outd = cand_d + ((size_t)q * NSPL + split) * KNB;
        int*   outi = cand_i + ((size_t)q * NSPL + split) * KNB;
        if (cnt <= CAPK) {
#pragma unroll 1
            for (int half = 0; half < 2; ++half) {
                int i = lane + 64 * half;
                if (i < cnt) {
                    float di = bufd[qi][i]; int xi = bufi[qi][i];
                    int rank = 0;
                    for (int t = 0; t < cnt; ++t) {
                        float dt = bufd[qi][t]; int xt = bufi[qi][t];
                        rank += (dt < di || (dt == di && xt < xi)) ? 1 : 0;
                    }
                    if (rank < KNB) { outd[rank] = di; outi[rank] = xi; }
                }
            }
        } else {
            knn_fullsplit_r17(base4, n0, m2x[j], m2y[j], m2z[j], lane, outd, outi);
        }
    }
}

// pre-BN pos/feat matmul for one (k,h) pair
__device__ __forceinline__ void prebn_r17(const float (*posf)[12], const float (*nf)[C_IN],
                                          int k, int h,
                                          const float* __restrict__ W_pos, const float* __restrict__ b_pos,
                                          const float* __restrict__ W_feat, const float* __restrict__ b_feat,
                                          float* a_out, float* f_out) {
    float4 p0 = *reinterpret_cast<const float4*>(&posf[k][0]);
    float4 p1 = *reinterpret_cast<const float4*>(&posf[k][4]);
    float p8 = posf[k][8], p9 = posf[k][9];
    float a = b_pos[h];
    a += p0.x * W_pos[0 * H_DIM + h]; a += p0.y * W_pos[1 * H_DIM + h];
    a += p0.z * W_pos[2 * H_DIM + h]; a += p0.w * W_pos[3 * H_DIM + h];
    a += p1.x * W_pos[4 * H_DIM + h]; a += p1.y * W_pos[5 * H_DIM + h];
    a += p1.z * W_pos[6 * H_DIM + h]; a += p1.w * W_pos[7 * H_DIM + h];
    a += p8 * W_pos[8 * H_DIM + h];   a += p9 * W_pos[9 * H_DIM + h];
    float f = b_feat[h];
#pragma unroll
    for (int j4 = 0; j4 < C_IN / 4; ++j4) {
        float4 c = *reinterpret_cast<const float4*>(&nf[k][j4 * 4]);
        f += c.x * W_feat[(j4 * 4 + 0) * H_DIM + h];
        f += c.y * W_feat[(j4 * 4 + 1) * H_DIM + h];
        f += c.z * W_feat[(j4 * 4 + 2) * H_DIM + h];
        f += c.w * W_feat[(j4 * 4 + 3) * H_DIM + h];
    }
    *a_out = a; *f_out = f;
}

// ---------------- stage A: merge cands + gather + pre-BN + combpre store + partials ----------------
__global__ __launch_bounds__(256) void stageA_r17(const float* __restrict__ xyz4,
                                                  const int* __restrict__ sample_idx,
                                                  const float* __restrict__ featsT,
                                                  const float* __restrict__ cand_d,
                                                  const int* __restrict__ cand_i,
                                                  const float* __restrict__ W_pos, const float* __restrict__ b_pos,
                                                  const float* __restrict__ W_feat, const float* __restrict__ b_feat,
                                                  const float* __restrict__ W_sc1, const float* __restrict__ W_sc2,
                                                  float* __restrict__ combpre,
                                                  float* __restrict__ sc1_pre, float* __restrict__ sc2_pre,
                                                  float* __restrict__ partialsA) {
    __shared__ int   idxs[4][KNB];
    __shared__ float sd[4][64];
    __shared__ int   si[4][64];
    __shared__ __align__(16) float posf[4][KNB][12];
    __shared__ __align__(16) float nf[4][KNB][C_IN];
    __shared__ float meanf[4][C_IN];
    __shared__ float centerf[4][C_IN];
    __shared__ float posS[4][H_DIM], posQ[4][H_DIM], featS[4][H_DIM], featQ[4][H_DIM];
    __shared__ float s1S[4][D_DIM], s1Q[4][D_DIM], s2S[4][D_DIM], s2Q[4][D_DIM];
    const int tid = threadIdx.x;
    const int w = tid >> 6, lane = tid & 63;
    const int q = blockIdx.x * 4 + w;
    const int b = q >> 12;
    const int sidx = clampi_r17(sample_idx[q], 0, NN - 1);
    const float* base4 = xyz4 + (size_t)b * NN * 4;

    // issue merge-independent loads up front (overlap latency with merge rank loop)
    float d = cand_d[(size_t)q * 64 + lane];
    int   i = cand_i[(size_t)q * 64 + lane];
    float qx = base4[(size_t)sidx * 4 + 0];
    float qy = base4[(size_t)sidx * 4 + 1];
    float qz = base4[(size_t)sidx * 4 + 2];
    float cfv = 0.f;
    if (lane < C_IN) cfv = featsT[((size_t)b * NN + sidx) * C_IN + lane];

    {
        sd[w][lane] = d; si[w][lane] = i;
        __syncthreads();
        int rank = 0;
#pragma unroll
        for (int t = 0; t < 64; ++t) {
            float dt = sd[w][t]; int it = si[w][t];
            rank += (dt < d || (dt == d && it < i)) ? 1 : 0;
        }
        if (rank < KNB) idxs[w][rank] = i;
        if (lane < C_IN) centerf[w][lane] = cfv;
        __syncthreads();
    }

    if (lane < KNB) {
        int idx = clampi_r17(idxs[w][lane], 0, NN - 1);
        float nx = base4[(size_t)idx * 4 + 0];
        float ny = base4[(size_t)idx * 4 + 1];
        float nz = base4[(size_t)idx * 4 + 2];
        float rx = qx - nx, ry = qy - ny, rz = qz - nz;
        float dist = sqrtf(rx * rx + ry * ry + rz * rz);
        posf[w][lane][0] = qx; posf[w][lane][1] = qy; posf[w][lane][2] = qz;
        posf[w][lane][3] = nx; posf[w][lane][4] = ny; posf[w][lane][5] = nz;
        posf[w][lane][6] = rx; posf[w][lane][7] = ry; posf[w][lane][8] = rz;
        posf[w][lane][9] = dist; posf[w][lane][10] = 0.f; posf[w][lane][11] = 0.f;
    }
    __syncthreads();
    const float* fT = featsT + (size_t)b * NN * C_IN;
#pragma unroll
    for (int ii = 0; ii < 2; ++ii) {
        int e4 = lane + 64 * ii;
        int k = e4 >> 3, c4 = e4 & 7;
        const float4 v = *reinterpret_cast<const float4*>(fT + (size_t)idxs[w][k] * C_IN + c4 * 4);
        *reinterpret_cast<float4*>(&nf[w][k][c4 * 4]) = v;
    }
    __syncthreads();

    const int h = lane & 31;
    float sP = 0.f, qP = 0.f, sF = 0.f, qF = 0.f;
    float* cp = combpre + (size_t)q * (KNB * D_DIM);
#pragma unroll
    for (int i2 = 0; i2 < 8; i2++) {
        int k = ((lane + 64 * i2) >> 5);
        float a, f;
        prebn_r17(posf[w], nf[w], k, h, W_pos, b_pos, W_feat, b_feat, &a, &f);
        sP += a; qP += a * a;
        sF += f; qF += f * f;
        cp[k * D_DIM + h] = f;
        cp[k * D_DIM + H_DIM + h] = a;
    }
    sP += __shfl_xor(sP, 32); qP += __shfl_xor(qP, 32);
    sF += __shfl_xor(sF, 32); qF += __shfl_xor(qF, 32);
    if (lane < H_DIM) {
        posS[w][h] = sP; posQ[w][h] = qP; featS[w][h] = sF; featQ[w][h] = qF;
    }
    if (lane < C_IN) {
        float s = 0.f;
#pragma unroll
        for (int k = 0; k < KNB; k++) s += nf[w][k][lane];
        meanf[w][lane] = s * (1.f / (float)KNB);
    }
    __syncthreads();
    {
        float a = 0.f, c2 = 0.f;
#pragma unroll
        for (int j = 0; j < C_IN; j++) {
            a  += meanf[w][j]   * W_sc1[j * D_DIM + lane];
            c2 += centerf[w][j] * W_sc2[j * D_DIM + lane];
        }
        sc1_pre[(size_t)q * D_DIM + lane] = a;
        sc2_pre[(size_t)q * D_DIM + lane] = c2;
        s1S[w][lane] = a;  s1Q[w][lane] = a * a;
        s2S[w][lane] = c2; s2Q[w][lane] = c2 * c2;
    }
    __syncthreads();
    float* row = partialsA + (size_t)blockIdx.x * PA_W;
    if (tid < H_DIM) {
        row[SPOS_SUM + tid]  = posS[0][tid] + posS[1][tid] + posS[2][tid] + posS[3][tid];
        row[SPOS_SQ + tid]   = posQ[0][tid] + posQ[1][tid] + posQ[2][tid] + posQ[3][tid];
        row[SFEAT_SUM + tid] = featS[0][tid] + featS[1][tid] + featS[2][tid] + featS[3][tid];
        row[SFEAT_SQ + tid]  = featQ[0][tid] + featQ[1][tid] + featQ[2][tid] + featQ[3][tid];
    } else if (tid >= 64 && tid < 128) {
        int dd = tid - 64;
        row[SSC1_SUM + dd] = s1S[0][dd] + s1S[1][dd] + s1S[2][dd] + s1S[3][dd];
        row[SSC1_SQ + dd]  = s1Q[0][dd] + s1Q[1][dd] + s1Q[2][dd] + s1Q[3][dd];
    } else if (tid >= 128 && tid < 192) {
        int dd = tid - 128;
        row[SSC2_SUM + dd] = s2S[0][dd] + s2S[1][dd] + s2S[2][dd] + s2S[3][dd];
        row[SSC2_SQ + dd]  = s2Q[0][dd] + s2Q[1][dd] + s2Q[2][dd] + s2Q[3][dd];
    }
}

// ---------------- generic split reduce ----------------
#define NRSPLIT 64
__global__ __launch_bounds__(256) void reduce_r17(const float* __restrict__ partials,
                                                  int rows, int width,
                                                  float* __restrict__ stats_out) {
    const int wchunks = (width + 255) / 256;
    const int wi = blockIdx.x % wchunks;
    const int pi = blockIdx.x / wchunks;
    const int c = wi * 256 + threadIdx.x;
    if (c >= width) return;
    const int per = rows / NRSPLIT;
    const int p0 = pi * per;
    float s = 0.f;
    for (int p = p0; p < p0 + per; ++p) s += partials[(size_t)p * width + c];
    atomicAdd(&stats_out[c], s);
}

// ---------------- stage B: stream combpre -> BN -> softmax -> pooled -> W_out ----------------
__global__ __launch_bounds__(256) void stageB_r17(const float* __restrict__ combpre,
                                                  const float* __restrict__ g_pos, const float* __restrict__ be_pos,
                                                  const float* __restrict__ g_feat, const float* __restrict__ be_feat,
                                                  const float* __restrict__ W_score, const float* __restrict__ W_out,
                                                  const float* __restrict__ stats,
                                                  float* __restrict__ out_pre,
                                                  float* __restrict__ partialsB) {
    __shared__ __align__(16) float comb[4][KNB][D_DIM];
    __shared__ float scl[D_DIM], shf[D_DIM];
    __shared__ float pooled[4][D_DIM];
    __shared__ float oS[4][D_DIM], oQ[4][D_DIM];
    const int tid = threadIdx.x;
    const int w = tid >> 6, lane = tid & 63;
    const int q = blockIdx.x * 4 + w;

    if (tid < D_DIM) {
        const float inv1 = 1.f / (float)(BB * MM * KNB);
        float mean, var, g, bb;
        if (tid < H_DIM) {
            mean = stats[SFEAT_SUM + tid] * inv1;
            var  = fmaxf(stats[SFEAT_SQ + tid] * inv1 - mean * mean, 0.f);
            g = g_feat[tid]; bb = be_feat[tid];
        } else {
            int h = tid - H_DIM;
            mean = stats[SPOS_SUM + h] * inv1;
            var  = fmaxf(stats[SPOS_SQ + h] * inv1 - mean * mean, 0.f);
            g = g_pos[h]; bb = be_pos[h];
        }
        float s = g * rsqrtf(var + EPSV);
        scl[tid] = s;
        shf[tid] = bb - mean * s;
    }
    __syncthreads();

    const float4* src = reinterpret_cast<const float4*>(combpre + (size_t)blockIdx.x * 4 * KNB * D_DIM);
#pragma unroll
    for (int i = 0; i < 4; ++i) {
        int f = tid + 256 * i;
        int qloc = f >> 8;
        int k = (f >> 4) & 15;
        int j4 = f & 15;
        float4 v = src[f];
        int j = j4 * 4;
        v.x = fmaxf(v.x * scl[j + 0] + shf[j + 0], 0.f);
        v.y = fmaxf(v.y * scl[j + 1] + shf[j + 1], 0.f);
        v.z = fmaxf(v.z * scl[j + 2] + shf[j + 2], 0.f);
        v.w = fmaxf(v.w * scl[j + 3] + shf[j + 3], 0.f);
        *reinterpret_cast<float4*>(&comb[qloc][k][j]) = v;
    }
    __syncthreads();

    const int d = lane;
    float s[KNB];
#pragma unroll
    for (int k = 0; k < KNB; k++) s[k] = 0.f;
#pragma unroll 4
    for (int j4 = 0; j4 < D_DIM / 4; ++j4) {
        float w0 = W_score[(j4 * 4 + 0) * D_DIM + d];
        float w1 = W_score[(j4 * 4 + 1) * D_DIM + d];
        float w2 = W_score[(j4 * 4 + 2) * D_DIM + d];
        float w3 = W_score[(j4 * 4 + 3) * D_DIM + d];
#pragma unroll
        for (int k = 0; k < KNB; k++) {
            float4 cb = *reinterpret_cast<const float4*>(&comb[w][k][j4 * 4]);
            s[k] += cb.x * w0 + cb.y * w1 + cb.z * w2 + cb.w * w3;
        }
    }
    float mx = s[0];
#pragma unroll
    for (int k = 1; k < KNB; k++) mx = fmaxf(mx, s[k]);
    float sum = 0.f;
#pragma unroll
    for (int k = 0; k < KNB; k++) { s[k] = __expf(s[k] - mx); sum += s[k]; }
    float inv = 1.f / sum;
    float pv = 0.f;
#pragma unroll
    for (int k = 0; k < KNB; k++) pv += s[k] * inv * comb[w][k][d];
    pooled[w][d] = pv;
    __syncthreads();
    float o = 0.f;
#pragma unroll
    for (int dd = 0; dd < D_DIM; dd++) o += pooled[w][dd] * W_out[dd * D_DIM + d];
    out_pre[(size_t)q * D_DIM + d] = o;
    oS[w][d] = o; oQ[w][d] = o * o;
    __syncthreads();
    float* row = partialsB + (size_t)blockIdx.x * PB_W;
    if (tid < D_DIM) {
        row[tid] = oS[0][tid] + oS[1][tid] + oS[2][tid] + oS[3][tid];
    } else if (tid < 2 * D_DIM) {
        int dd = tid - D_DIM;
        row[D_DIM + dd] = oQ[0][dd] + oQ[1][dd] + oQ[2][dd] + oQ[3][dd];
    }
}

// ---------------- final ----------------
__global__ __launch_bounds__(256) void final_r17(const float* __restrict__ out_pre,
                                                 const float* __restrict__ sc1_pre,
                                                 const float* __restrict__ sc2_pre,
                                                 const float* __restrict__ stats,
                                                 const float* __restrict__ g_out, const float* __restrict__ be_out,
                                                 const float* __restrict__ g_sc1, const float* __restrict__ be_sc1,
                                                 const float* __restrict__ g_sc2, const float* __restrict__ be_sc2,
                                                 float* __restrict__ out) {
    __shared__ float yt[64][65];
    const int tid = threadIdx.x;
    const int blk = blockIdx.x;
    const int b = blk >> 6;
    const int m0 = (blk & 63) * 64;
    const int d = tid & 63;

    const float invn = 1.f / (float)(BB * MM);
    float mo = stats[SOUT_SUM + d] * invn;
    float vo = fmaxf(stats[SOUT_SQ + d] * invn - mo * mo, 0.f);
    float so = g_out[d] * rsqrtf(vo + EPSV);
    float oo = be_out[d] - mo * so;
    float m1 = stats[SSC1_SUM + d] * invn;
    float v1 = fmaxf(stats[SSC1_SQ + d] * invn - m1 * m1, 0.f);
    float s1 = g_sc1[d] * rsqrtf(v1 + EPSV);
    float o1 = be_sc1[d] - m1 * s1;
    float m2 = stats[SSC2_SUM + d] * invn;
    float v2 = fmaxf(stats[SSC2_SQ + d] * invn - m2 * m2, 0.f);
    float s2 = g_sc2[d] * rsqrtf(v2 + EPSV);
    float o2 = be_sc2[d] - m2 * s2;

#pragma unroll
    for (int p = 0; p < 16; p++) {
        int ml = (tid >> 6) + 4 * p;
        size_t q = (size_t)b * MM + m0 + ml;
        float x_out = fmaxf(out_pre[q * D_DIM + d] * so + oo, 0.f);
        float x1 = sc1_pre[q * D_DIM + d] * s1 + o1;
        float x2 = sc2_pre[q * D_DIM + d] * s2 + o2;
        yt[ml][d] = fmaxf(x_out + x1 + x2, 0.f);
    }
    __syncthreads();
#pragma unroll
    for (int p = 0; p < 16; p++) {
        int dr = (tid >> 6) + 4 * p;
        int mc = tid & 63;
        out[BB * MM * 3 + (size_t)b * (D_DIM * MM) + (size_t)dr * MM + m0 + mc] = yt[mc][dr];
    }
}

extern "C" void kernel_launch(void* const* d_in, const int* in_sizes, int n_in,
                              void* d_out, int out_size, void* d_ws, size_t ws_size,
                              hipStream_t stream) {
    const float* xyz        = (const float*)d_in[0];
    const float* feats      = (const float*)d_in[1];
    const int*   sample_idx = (const int*)d_in[2];
    const float* W_pos  = (const float*)d_in[3];
    const float* b_pos  = (const float*)d_in[4];
    const float* g_pos  = (const float*)d_in[5];
    const float* be_pos = (const float*)d_in[6];
    const float* W_feat  = (const float*)d_in[7];
    const float* b_feat  = (const float*)d_in[8];
    const float* g_feat  = (const float*)d_in[9];
    const float* be_feat = (const float*)d_in[10];
    const float* W_score = (const float*)d_in[11];
    const float* W_out  = (const float*)d_in[12];
    const float* g_out  = (const float*)d_in[13];
    const float* be_out = (const float*)d_in[14];
    const float* W_sc1  = (const float*)d_in[15];
    const float* g_sc1  = (const float*)d_in[16];
    const float* be_sc1 = (const float*)d_in[17];
    const float* W_sc2  = (const float*)d_in[18];
    const float* g_sc2  = (const float*)d_in[19];
    const float* be_sc2 = (const float*)d_in[20];

    float* out = (float*)d_out;
    float* ws = (float*)d_ws;

    float* featsT    = ws;                                   // 1,048,576
    float* xyz4      = featsT + 1048576;                     //   131,072
    float* sc1_pre   = xyz4 + 131072;                        //   524,288
    float* sc2_pre   = sc1_pre + 524288;                     //   524,288
    float* out_pre   = sc2_pre + 524288;                     //   524,288
    float* stats     = out_pre + 524288;                     //       512
    float* partialsA = stats + STATS_LEN;                    //   786,432
    float* partialsB = partialsA + NBLK * PA_W;              //   262,144
    float* cand_d    = partialsB + NBLK * PB_W;              //   524,288
    int*   cand_i    = (int*)(cand_d + (size_t)BB * MM * NSPL * KNB);   // 524,288 ints
    float* combpre   = (float*)(cand_i + (size_t)BB * MM * NSPL * KNB); // 8,388,608 (32 MB)

    prep_r17<<<BB * (NN / 64), 256, 0, stream>>>(feats, xyz, sample_idx,
                                                 featsT, xyz4, stats, out);

    knn_r17<<<(BB * MM / 16) * NSPL, 256, 0, stream>>>(xyz4, sample_idx, cand_d, cand_i);

    stageA_r17<<<NBLK, 256, 0, stream>>>(xyz4, sample_idx, featsT, cand_d, cand_i,
                                         W_pos, b_pos, W_feat, b_feat, W_sc1, W_sc2,
                                         combpre, sc1_pre, sc2_pre, partialsA);
    reduce_r17<<<2 * NRSPLIT, 256, 0, stream>>>(partialsA, NBLK, PA_W, stats);

    stageB_r17<<<NBLK, 256, 0, stream>>>(combpre,
                                         g_pos, be_pos, g_feat, be_feat,
                                         W_score, W_out, stats, out_pre, partialsB);
    reduce_r17<<<1 * NRSPLIT, 256, 0, stream>>>(partialsB, NBLK, PB_W, stats + SOUT_SUM);

    final_r17<<<BB * (MM / 64), 256, 0, stream>>>(out_pre, sc1_pre, sc2_pre, stats,
                                                  g_out, be_out, g_sc1, be_sc1, g_sc2, be_sc2, out);
}